// Round 8
// baseline (151.214 us; speedup 1.0000x reference)
//
#include <hip/hip_runtime.h>
#include <stdint.h>

// Problem constants: B=4, T=512, S=256, V=50257.
#define DIM_B 4
#define DIM_T 512
#define DIM_S 256
#define DIM_V 50257
#define NROW   (DIM_B * DIM_T)       // 2048
#define NCHUNK 25731584u             // NROW*DIM_V/4 (exact)
#define NT     524288u               // stream threads (2048 blocks x 256), pow2
#define NTMSK  (NT - 1u)
#define DEPTH  4

// ws layout (bytes):
//   [0]              ocnt        (int, zeroed by memset)
//   [64]             cnt[NT]     (int, zeroed by memset)      2 MB
//   [64+4NT]         keys[NT*4]  (uint32 element index e)     8 MB
//   [64+20NT]        vals[NT*4]  (float)                      8 MB
//   [64+36NT]        okey[NT]    (uint32)                     2 MB
//   [64+40NT]        oval[NT]    (float)                      2 MB
#define WS_NEEDED (64 + 44ull * NT)

// ---- K1: route each raw (e, p) entry to its stream-thread's slot ----
// No dedupe: duplicates become two additive slots (exact; fp add commutative).
__global__ __launch_bounds__(256) void build_kernel(
    const float* __restrict__ p_pos, const int* __restrict__ src,
    int* __restrict__ cnt, uint32_t* __restrict__ keys, float* __restrict__ vals,
    int* __restrict__ ocnt, uint32_t* __restrict__ okey, float* __restrict__ oval)
{
    const int row = blockIdx.x;            // row = b*T + t
    const int b   = row >> 9;              // T = 512
    const int tid = threadIdx.x;

    const int      v = src[b * DIM_S + tid];
    const float    p = p_pos[(size_t)row * DIM_S + tid];
    const uint32_t e = (uint32_t)row * DIM_V + (uint32_t)v;   // < 2^27
    const uint32_t t = (e >> 2) & NTMSK;                      // owning thread

    const int j = atomicAdd(&cnt[t], 1);
    if (j < DEPTH) {
        keys[t * DEPTH + j] = e;
        vals[t * DEPTH + j] = p;
    } else {
        const int oj = atomicAdd(ocnt, 1);
        okey[oj] = e;
        oval[oj] = p;
    }
}

// ---- K2: flat grid-stride single-touch stream, NO loads in the loop ----
// Thread t owns chunks g = t, t+NT, ... (fill-identical whole-GPU write front:
// each sweep writes one contiguous 8 MB window). Patches live in registers:
// per iteration 4 compares + selects + adds, then one float4 store.
__global__ __launch_bounds__(256) void stream_kernel(
    const int* __restrict__ cnt, const uint32_t* __restrict__ keys,
    const float* __restrict__ vals, float4* __restrict__ out4)
{
    const uint32_t t = blockIdx.x * 256u + threadIdx.x;
    const int      c = cnt[t];
    const uint4  K = ((const uint4*)keys)[t];    // one dwordx4
    const float4 W = ((const float4*)vals)[t];   // one dwordx4

    // chunk keys (sentinel never matches g < 2^25) + lane-expanded patches
    uint32_t kc0 = 0xFFFFFFFFu, kc1 = 0xFFFFFFFFu, kc2 = 0xFFFFFFFFu, kc3 = 0xFFFFFFFFu;
    float4 P0 = make_float4(0.f,0.f,0.f,0.f), P1 = P0, P2 = P0, P3 = P0;
    if (c > 0) { kc0 = K.x >> 2; const int l = K.x & 3;
        P0.x = l==0?W.x:0.f; P0.y = l==1?W.x:0.f; P0.z = l==2?W.x:0.f; P0.w = l==3?W.x:0.f; }
    if (c > 1) { kc1 = K.y >> 2; const int l = K.y & 3;
        P1.x = l==0?W.y:0.f; P1.y = l==1?W.y:0.f; P1.z = l==2?W.y:0.f; P1.w = l==3?W.y:0.f; }
    if (c > 2) { kc2 = K.z >> 2; const int l = K.z & 3;
        P2.x = l==0?W.z:0.f; P2.y = l==1?W.z:0.f; P2.z = l==2?W.z:0.f; P2.w = l==3?W.z:0.f; }
    if (c > 3) { kc3 = K.w >> 2; const int l = K.w & 3;
        P3.x = l==0?W.w:0.f; P3.y = l==1?W.w:0.f; P3.z = l==2?W.w:0.f; P3.w = l==3?W.w:0.f; }

    #pragma unroll 4
    for (uint32_t g = t; g < NCHUNK; g += NT) {
        float4 o;
        o.x = (g==kc0?P0.x:0.f) + (g==kc1?P1.x:0.f) + (g==kc2?P2.x:0.f) + (g==kc3?P3.x:0.f);
        o.y = (g==kc0?P0.y:0.f) + (g==kc1?P1.y:0.f) + (g==kc2?P2.y:0.f) + (g==kc3?P3.y:0.f);
        o.z = (g==kc0?P0.z:0.f) + (g==kc1?P1.z:0.f) + (g==kc2?P2.z:0.f) + (g==kc3?P3.z:0.f);
        o.w = (g==kc0?P0.w:0.f) + (g==kc1?P1.w:0.f) + (g==kc2?P2.w:0.f) + (g==kc3?P3.w:0.f);
        out4[g] = o;
    }
}

// ---- K3: apply overflow entries (runs after K2 -> no ordering hazard) ----
__global__ __launch_bounds__(256) void overflow_kernel(
    const int* __restrict__ ocnt, const uint32_t* __restrict__ okey,
    const float* __restrict__ oval, float* __restrict__ out)
{
    const int n = *ocnt;
    const int stride = gridDim.x * 256;
    for (int i = blockIdx.x * 256 + threadIdx.x; i < n; i += stride)
        atomicAdd(out + okey[i], oval[i]);
}

// ---- Fallback: R7 single-kernel one-pass (proven 88.7 us) if ws too small ----
__global__ __launch_bounds__(256) void onepass_kernel(
    const float* __restrict__ p_pos, const int* __restrict__ src,
    float* __restrict__ out)
{
    __shared__ uint32_t bkey[256][DEPTH];
    __shared__ float    bval[256][DEPTH];
    __shared__ int      bcnt[256];
    __shared__ uint32_t okey[DIM_S];
    __shared__ float    oval[DIM_S];
    __shared__ int      ocnt;

    const int row = blockIdx.x;
    const int b   = row >> 9;
    const int tid = threadIdx.x;

    bcnt[tid] = 0;
    if (tid == 0) ocnt = 0;
    __syncthreads();

    const long long rb   = (long long)row * DIM_V;
    const int head  = (int)((4 - (row & 3)) & 3);
    const int nvec  = (DIM_V - head) >> 2;
    const int ntail = DIM_V - head - (nvec << 2);

    {
        const int   v = src[b * DIM_S + tid];
        const float p = p_pos[(size_t)row * DIM_S + tid];
        const int   d = v - head;
        bool to_ovf = true;
        if (d >= 0 && d < (nvec << 2)) {
            const int c = d >> 2;
            const int t = c & 255;
            const int j = atomicAdd(&bcnt[t], 1);
            if (j < DEPTH) { bkey[t][j] = (uint32_t)d; bval[t][j] = p; to_ovf = false; }
        }
        if (to_ovf) { const int j = atomicAdd(&ocnt, 1); okey[j] = (uint32_t)v; oval[j] = p; }
    }
    __syncthreads();

    uint32_t k0 = 0xFFFFFFFFu, k1 = 0xFFFFFFFFu, k2 = 0xFFFFFFFFu, k3 = 0xFFFFFFFFu;
    float    v0 = 0.f, v1 = 0.f, v2 = 0.f, v3 = 0.f;
    {
        const int cnt = bcnt[tid];
        if (cnt > 0) { k0 = bkey[tid][0]; v0 = bval[tid][0]; }
        if (cnt > 1) { k1 = bkey[tid][1]; v1 = bval[tid][1]; }
        if (cnt > 2) { k2 = bkey[tid][2]; v2 = bval[tid][2]; }
        if (cnt > 3) { k3 = bkey[tid][3]; v3 = bval[tid][3]; }
    }

    float* __restrict__ rowp = out + rb;
    if (tid < head)  rowp[tid] = 0.0f;
    if (tid < ntail) rowp[head + (nvec << 2) + tid] = 0.0f;

    float4* __restrict__ vp = (float4*)(rowp + head);
    #pragma unroll 2
    for (int cc = tid; cc < nvec; cc += 256) {
        const uint32_t d0 = (uint32_t)(cc << 2);
        float4 o;
        o.x = ((k0==d0    )?v0:0.f) + ((k1==d0    )?v1:0.f) + ((k2==d0    )?v2:0.f) + ((k3==d0    )?v3:0.f);
        o.y = ((k0==d0+1u)?v0:0.f) + ((k1==d0+1u)?v1:0.f) + ((k2==d0+1u)?v2:0.f) + ((k3==d0+1u)?v3:0.f);
        o.z = ((k0==d0+2u)?v0:0.f) + ((k1==d0+2u)?v1:0.f) + ((k2==d0+2u)?v2:0.f) + ((k3==d0+2u)?v3:0.f);
        o.w = ((k0==d0+3u)?v0:0.f) + ((k1==d0+3u)?v1:0.f) + ((k2==d0+3u)?v2:0.f) + ((k3==d0+3u)?v3:0.f);
        vp[cc] = o;
    }

    __syncthreads();
    for (int i = tid; i < ocnt; i += 256)
        atomicAdd(rowp + okey[i], oval[i]);
}

extern "C" void kernel_launch(void* const* d_in, const int* in_sizes, int n_in,
                              void* d_out, int out_size, void* d_ws, size_t ws_size,
                              hipStream_t stream) {
    const float* p_pos = (const float*)d_in[0];   // [B,T,S]
    // d_in[1] = p_target_vocab — dead data (shape-only in the reference).
    const int*   src   = (const int*)d_in[2];     // [B,S]
    float*       out   = (float*)d_out;           // [B,T,V]

    if (ws_size >= WS_NEEDED) {
        char* base = (char*)d_ws;
        int*      ocnt = (int*)base;
        int*      cnt  = (int*)(base + 64);
        uint32_t* keys = (uint32_t*)(base + 64 + 4ull * NT);
        float*    vals = (float*)(base + 64 + 20ull * NT);
        uint32_t* okey = (uint32_t*)(base + 64 + 36ull * NT);
        float*    oval = (float*)(base + 64 + 40ull * NT);

        // K0: zero ocnt + cnt[] (graph memset node, ~2 MB)
        hipMemsetAsync(d_ws, 0, 64 + 4ull * NT, stream);
        // K1: route entries to stream-thread slots
        build_kernel<<<NROW, DIM_S, 0, stream>>>(p_pos, src, cnt, keys, vals, ocnt, okey, oval);
        // K2: flat single-touch stream (fill-identical front, load-free loop)
        stream_kernel<<<NT / 256, 256, 0, stream>>>(cnt, keys, vals, (float4*)out);
        // K3: overflow patches
        overflow_kernel<<<32, 256, 0, stream>>>(ocnt, okey, oval, out);
    } else {
        onepass_kernel<<<NROW, DIM_S, 0, stream>>>(p_pos, src, out);
    }
}

// Round 9
// 90.865 us; speedup vs baseline: 1.6642x; 1.6642x over previous
//
#include <hip/hip_runtime.h>
#include <stdint.h>

// Problem constants (from reference): B=4, T=512, S=256, V=50257.
#define DIM_B 4
#define DIM_T 512
#define DIM_S 256
#define DIM_V 50257
#define DEPTH 4            // register patch slots per thread (Poisson(1): P(>4)~0.4%)
#define NRPB  4            // rows per block -> 512 blocks = 2 blocks/CU = 8 waves/CU

// R7's proven single-touch structure at LOW OCCUPANCY (the one untested lever).
// 512 blocks x 256 threads; each block streams 4 consecutive rows. Per row:
//   Phase 1 (route): each thread pushes its raw (v,p) into the LDS bucket of
//     the thread that streams chunk c=(v-head)>>2 (owner = c & 255). No dedupe;
//     duplicates are additive register patches. Head/tail/overflow -> LDS list.
//   Phase 2 (stream): pure-store float4 loop, patches in registers
//     (4 compare/select per lane). No loads, no waitcnt in the loop.
//   Phase 3 (overflow): barrier (drains vmcnt -> stores at L2), then row-local
//     atomicAdd patches (exec at L2, race-free: addresses only in own row).
__global__ __launch_bounds__(256) void onepass4_kernel(
    const float* __restrict__ p_pos,   // [B, T, S]
    const int*   __restrict__ src,     // [B, S]  (int64 narrowed to int32)
    float*       __restrict__ out)     // [B, T, V]
{
    __shared__ uint32_t bkey[256][DEPTH];   // middle-local elem offset d
    __shared__ float    bval[256][DEPTH];
    __shared__ int      bcnt[256];
    __shared__ uint32_t okey[DIM_S];        // overflow: row-local elem v
    __shared__ float    oval[DIM_S];
    __shared__ int      ocnt;

    const int tid = threadIdx.x;            // s index (S == blockDim.x == 256)

    #pragma unroll 1
    for (int r = 0; r < NRPB; ++r) {
        const int row = (blockIdx.x << 2) | r;   // row = b*T + t
        const int b   = row >> 9;                // T = 512

        // ---- reset LDS ----
        bcnt[tid] = 0;
        if (tid == 0) ocnt = 0;
        __syncthreads();

        const long long rb   = (long long)row * DIM_V;
        const int head  = (int)((4 - (row & 3)) & 3);   // 50257 % 4 == 1
        const int nvec  = (DIM_V - head) >> 2;          // 12563 or 12564 chunks
        const int ntail = DIM_V - head - (nvec << 2);   // 0..3

        // ---- Phase 1: route this thread's entry ----
        {
            const int   v = src[b * DIM_S + tid];
            const float p = p_pos[(size_t)row * DIM_S + tid];
            const int   d = v - head;                   // middle-local offset
            bool to_ovf = true;
            if (d >= 0 && d < (nvec << 2)) {
                const int c = d >> 2;                   // chunk index
                const int t = c & 255;                  // owning thread
                const int j = atomicAdd(&bcnt[t], 1);
                if (j < DEPTH) { bkey[t][j] = (uint32_t)d; bval[t][j] = p; to_ovf = false; }
            }
            if (to_ovf) {
                const int j = atomicAdd(&ocnt, 1);
                okey[j] = (uint32_t)v; oval[j] = p;
            }
        }
        __syncthreads();

        // ---- pull register patches (sentinel never matches d <= 50255) ----
        uint32_t k0 = 0xFFFFFFFFu, k1 = 0xFFFFFFFFu, k2 = 0xFFFFFFFFu, k3 = 0xFFFFFFFFu;
        float    v0 = 0.0f, v1 = 0.0f, v2 = 0.0f, v3 = 0.0f;
        {
            const int cnt = bcnt[tid];                  // may exceed DEPTH
            if (cnt > 0) { k0 = bkey[tid][0]; v0 = bval[tid][0]; }
            if (cnt > 1) { k1 = bkey[tid][1]; v1 = bval[tid][1]; }
            if (cnt > 2) { k2 = bkey[tid][2]; v2 = bval[tid][2]; }
            if (cnt > 3) { k3 = bkey[tid][3]; v3 = bval[tid][3]; }
        }

        float* __restrict__ rowp = out + rb;

        // scalar head/tail (patched later by overflow atomics if targeted)
        if (tid < head)  rowp[tid] = 0.0f;
        if (tid < ntail) rowp[head + (nvec << 2) + tid] = 0.0f;

        // ---- Phase 2: pure-store stream with register compares ----
        float4* __restrict__ vp = (float4*)(rowp + head);
        #pragma unroll 2
        for (int c = tid; c < nvec; c += 256) {
            const uint32_t d0 = (uint32_t)(c << 2);
            float4 o;
            o.x = ((k0 == d0     ) ? v0 : 0.0f) + ((k1 == d0     ) ? v1 : 0.0f)
                + ((k2 == d0     ) ? v2 : 0.0f) + ((k3 == d0     ) ? v3 : 0.0f);
            o.y = ((k0 == d0 + 1u) ? v0 : 0.0f) + ((k1 == d0 + 1u) ? v1 : 0.0f)
                + ((k2 == d0 + 1u) ? v2 : 0.0f) + ((k3 == d0 + 1u) ? v3 : 0.0f);
            o.z = ((k0 == d0 + 2u) ? v0 : 0.0f) + ((k1 == d0 + 2u) ? v1 : 0.0f)
                + ((k2 == d0 + 2u) ? v2 : 0.0f) + ((k3 == d0 + 2u) ? v3 : 0.0f);
            o.w = ((k0 == d0 + 3u) ? v0 : 0.0f) + ((k1 == d0 + 3u) ? v1 : 0.0f)
                + ((k2 == d0 + 3u) ? v2 : 0.0f) + ((k3 == d0 + 3u) ? v3 : 0.0f);
            vp[c] = o;
        }

        // ---- Phase 3: overflow (barrier drains vmcnt; atomics exec at L2) ----
        __syncthreads();
        {
            const int n = ocnt;
            for (int i = tid; i < n; i += 256)
                atomicAdd(rowp + okey[i], oval[i]);
        }
        __syncthreads();   // protect okey/oval/ocnt before next row's reset
    }
}

extern "C" void kernel_launch(void* const* d_in, const int* in_sizes, int n_in,
                              void* d_out, int out_size, void* d_ws, size_t ws_size,
                              hipStream_t stream) {
    const float* p_pos = (const float*)d_in[0];   // [B,T,S]
    // d_in[1] = p_target_vocab — dead data (shape-only in the reference).
    const int*   src   = (const int*)d_in[2];     // [B,S]
    float*       out   = (float*)d_out;           // [B,T,V]

    onepass4_kernel<<<(DIM_B * DIM_T) / NRPB, DIM_S, 0, stream>>>(p_pos, src, out);
}